// Round 1
// baseline (2079.480 us; speedup 1.0000x reference)
//
#include <hip/hip_runtime.h>

#define N_NODES 50000
#define N_EDGES 800000
#define DD 128

typedef __bf16 bf16x8 __attribute__((ext_vector_type(8)));
typedef float f32x4 __attribute__((ext_vector_type(4)));

// ---------------- workspace layout (bytes) ----------------
// total ~282 MB
static const size_t WT_OFF    = 0;                       // 114688 bf16 (transposed weights)
static const size_t STATS_OFF = 229376;                  // 1024 floats
static const size_t LAST_OFF  = 233472;                  // 50000 ints
static const size_t HBF_OFF   = 433664;                  // h as bf16, 6.4M elems
static const size_t PBF_OFF   = HBF_OFF + 12800000;      // p as bf16
static const size_t AGGH_OFF  = PBF_OFF + 12800000;      // 6.4M floats
static const size_t AGGP_OFF  = AGGH_OFF + 25600000;     // 6.4M floats (adjacent to AGGH)
static const size_t ETA_OFF   = AGGP_OFF + 25600000;     // 102.4M bf16

// transposed-weight pack sub-offsets (elements). layout: Wt[n][k] (row per output col)
#define WLIN_T 0
#define WHPR_T 16384
#define WP2_T  49152
#define WHPS_T 65536
#define WP1_T  98304

// ---------------- helpers ----------------
__device__ __forceinline__ unsigned short f2bf(float x){
  unsigned u = __float_as_uint(x);
  u = (u + 0x7fffu + ((u >> 16) & 1u)) >> 16;
  return (unsigned short)u;
}
__device__ __forceinline__ unsigned packbf2(float a, float b){
  return (unsigned)f2bf(a) | ((unsigned)f2bf(b) << 16);
}
__device__ __forceinline__ float bf2f(unsigned short v){
  return __uint_as_float(((unsigned)v) << 16);
}

// MFMA over 8 col-tiles, K=128. Arow points at the lane's A row (already +k offset).
// W is [128][136] bf16 in LDS, Wt layout (row = output col, 8 contiguous k per quad).
__device__ __forceinline__ void mfma_tile8(const unsigned short* Arow,
                                           const unsigned short* W,
                                           const int mm, const int q, f32x4* acc)
{
#pragma unroll
  for (int s = 0; s < 4; ++s){
    bf16x8 a = *(const bf16x8*)(Arow + s*32 + q*8);
#pragma unroll
    for (int c = 0; c < 8; ++c){
      bf16x8 b = *(const bf16x8*)(W + (c*16 + mm)*136 + s*32 + q*8);
      acc[c] = __builtin_amdgcn_mfma_f32_16x16x32_bf16(a, b, acc[c], 0, 0, 0);
    }
  }
}

// ---------------- K0a: transpose weights to bf16 Wt[n][k] ----------------
__global__ __launch_bounds__(256) void k0a_weights(
    const float* __restrict__ Wlin, const float* __restrict__ Whpr,
    const float* __restrict__ Wp2,  const float* __restrict__ Whps,
    const float* __restrict__ Wp1,  unsigned short* __restrict__ wt)
{
  int i = blockIdx.x * 256 + threadIdx.x;
  if (i >= 114688) return;
  float v;
  if (i < 16384)      { int j = i;         int n = j >> 7, k = j & 127; v = Wlin[k*128 + n]; }
  else if (i < 49152) { int j = i - 16384; int n = j >> 8, k = j & 255; v = Whpr[k*128 + n]; }
  else if (i < 65536) { int j = i - 49152; int n = j >> 7, k = j & 127; v = Wp2 [k*128 + n]; }
  else if (i < 98304) { int j = i - 65536; int n = j >> 8, k = j & 255; v = Whps[k*128 + n]; }
  else                { int j = i - 98304; int n = j >> 7, k = j & 127; v = Wp1 [k*128 + n]; }
  wt[i] = f2bf(v);
}

// ---------------- K0b: h,p -> bf16 copies ----------------
__global__ __launch_bounds__(256) void k0b_cast(
    const float* __restrict__ h, const float* __restrict__ p,
    unsigned short* __restrict__ hbf, unsigned short* __restrict__ pbf)
{
  int i = blockIdx.x * 256 + threadIdx.x;   // 3.2M threads, 4 floats each
  const float4* src; uint2* dst;
  if (i < 1600000){ src = (const float4*)h + i; dst = (uint2*)hbf + i; }
  else            { int j = i - 1600000; src = (const float4*)p + j; dst = (uint2*)pbf + j; }
  float4 v = *src;
  uint2 o; o.x = packbf2(v.x, v.y); o.y = packbf2(v.z, v.w);
  *dst = o;
}

// ---------------- K2: fused edge kernel ----------------
struct SmemK2 {
  alignas(16) unsigned short X [128*136];  // X = hs+hr+e (bf16); reused as eta dump
  alignas(16) unsigned short HR[128*136];
  alignas(16) unsigned short PR[128*136];
  alignas(16) unsigned short W [128*136];
  int   recIdx[128];
  float stat[256];
};

__global__ __launch_bounds__(512, 2) void k2_edge(
    const float* __restrict__ e,
    const int*   __restrict__ eidx,
    const float* __restrict__ b_lin,
    const float* __restrict__ b_hpr,
    const float* __restrict__ b_p2,
    const unsigned short* __restrict__ hbf,
    const unsigned short* __restrict__ pbf,
    const unsigned short* __restrict__ wt,
    unsigned short* __restrict__ etaOut,
    float* __restrict__ aggH,
    float* __restrict__ aggP,
    int*   __restrict__ lastE,
    float* __restrict__ gstats)
{
  __shared__ SmemK2 sm;
  const int t  = threadIdx.x;
  const int e0 = blockIdx.x * 128;
  const int row = t >> 2, part = t & 3;
  const int er  = e0 + row;
  const int snd = eidx[er];
  const int rcv = eidx[N_EDGES + er];
  if (part == 0) sm.recIdx[row] = rcv;
  if (t < 256)  sm.stat[t] = 0.f;

  // ---- stage gathered rows ----
  {
    const uint4*  hs4 = (const uint4*)(hbf + (size_t)snd*DD + part*32);
    const uint4*  hr4 = (const uint4*)(hbf + (size_t)rcv*DD + part*32);
    const uint4*  pr4 = (const uint4*)(pbf + (size_t)rcv*DD + part*32);
    const float4* ee4 = (const float4*)(e  + (size_t)er *DD + part*32);
    uint4* dHR = (uint4*)&sm.HR[row*136 + part*32];
    uint4* dPR = (uint4*)&sm.PR[row*136 + part*32];
    uint4* dX  = (uint4*)&sm.X [row*136 + part*32];
#pragma unroll
    for (int j = 0; j < 4; ++j){
      uint4 a = hs4[j], b = hr4[j];
      dHR[j] = b; dPR[j] = pr4[j];
      float4 elo = ee4[2*j], ehi = ee4[2*j+1];
      uint4 o;
      o.x = packbf2(bf2f((unsigned short)(a.x & 0xffffu)) + bf2f((unsigned short)(b.x & 0xffffu)) + elo.x,
                    bf2f((unsigned short)(a.x >> 16))     + bf2f((unsigned short)(b.x >> 16))     + elo.y);
      o.y = packbf2(bf2f((unsigned short)(a.y & 0xffffu)) + bf2f((unsigned short)(b.y & 0xffffu)) + elo.z,
                    bf2f((unsigned short)(a.y >> 16))     + bf2f((unsigned short)(b.y >> 16))     + elo.w);
      o.z = packbf2(bf2f((unsigned short)(a.z & 0xffffu)) + bf2f((unsigned short)(b.z & 0xffffu)) + ehi.x,
                    bf2f((unsigned short)(a.z >> 16))     + bf2f((unsigned short)(b.z >> 16))     + ehi.y);
      o.w = packbf2(bf2f((unsigned short)(a.w & 0xffffu)) + bf2f((unsigned short)(b.w & 0xffffu)) + ehi.z,
                    bf2f((unsigned short)(a.w >> 16))     + bf2f((unsigned short)(b.w >> 16))     + ehi.w);
      dX[j] = o;
    }
  }
  // stage W_lin^T
  {
    const uint4* srcw = (const uint4*)(wt + WLIN_T + row*128 + part*32);
    uint4* dstw = (uint4*)&sm.W[row*136 + part*32];
#pragma unroll
    for (int j = 0; j < 4; ++j) dstw[j] = srcw[j];
  }
  if (part == 0) atomicMax(&lastE[snd], er);   // last-write-wins resolution
  __syncthreads();

  const int lane = t & 63;
  const int wv = t >> 6;
  const int mm = lane & 15;
  const int q  = lane >> 4;
  const int rw = wv * 16;

  f32x4 acc[8];
#pragma unroll
  for (int c = 0; c < 8; ++c) acc[c] = (f32x4){0.f,0.f,0.f,0.f};

  // ---- phase 1: eta ----
  mfma_tile8(&sm.X[(rw+mm)*136], sm.W, mm, q, acc);

  float rs0=0.f, rs1=0.f, rs2=0.f, rs3=0.f;
#pragma unroll
  for (int c = 0; c < 8; ++c){
    float b3 = 3.f * b_lin[c*16 + mm];
#pragma unroll
    for (int g = 0; g < 4; ++g){
      float z = acc[c][g] + b3;
      acc[c][g] = 1.f / (1.f + __expf(-z));      // eta
    }
    rs0 += acc[c][0]; rs1 += acc[c][1]; rs2 += acc[c][2]; rs3 += acc[c][3];
  }
#pragma unroll
  for (int msk = 1; msk < 16; msk <<= 1){
    rs0 += __shfl_xor(rs0, msk); rs1 += __shfl_xor(rs1, msk);
    rs2 += __shfl_xor(rs2, msk); rs3 += __shfl_xor(rs3, msk);
  }
  const float inv0 = 1.f/rs0, inv1 = 1.f/rs1, inv2 = 1.f/rs2, inv3 = 1.f/rs3;

  float en[8][4];
#pragma unroll
  for (int c = 0; c < 8; ++c){
    float s1 = acc[c][0] + acc[c][1] + acc[c][2] + acc[c][3];
    float s2 = acc[c][0]*acc[c][0] + acc[c][1]*acc[c][1] + acc[c][2]*acc[c][2] + acc[c][3]*acc[c][3];
    s1 += __shfl_xor(s1, 16); s1 += __shfl_xor(s1, 32);
    s2 += __shfl_xor(s2, 16); s2 += __shfl_xor(s2, 32);
    if (q == 0){
      atomicAdd(&sm.stat[c*16 + mm], s1);
      atomicAdd(&sm.stat[128 + c*16 + mm], s2);
    }
#pragma unroll
    for (int g = 0; g < 4; ++g)
      sm.X[(rw + q*4 + g)*136 + c*16 + mm] = f2bf(acc[c][g]);   // eta dump
    en[c][0] = acc[c][0]*inv0; en[c][1] = acc[c][1]*inv1;
    en[c][2] = acc[c][2]*inv2; en[c][3] = acc[c][3]*inv3;
  }
  __syncthreads();

  // ---- store eta to global; stage Whpr^T half0 ----
  {
    const uint4* srcX = (const uint4*)&sm.X[row*136 + part*32];
    uint4* dstE = (uint4*)(etaOut + (size_t)er*DD + part*32);
#pragma unroll
    for (int j = 0; j < 4; ++j) dstE[j] = srcX[j];
    const uint4* srcw = (const uint4*)(wt + WHPR_T + row*256 + part*32);
    uint4* dstw = (uint4*)&sm.W[row*136 + part*32];
#pragma unroll
    for (int j = 0; j < 4; ++j) dstw[j] = srcw[j];
  }
  __syncthreads();

  // ---- phase 2a: hp_rec += h_r @ Whpr[k<128] ----
#pragma unroll
  for (int c = 0; c < 8; ++c) acc[c] = (f32x4){0.f,0.f,0.f,0.f};
  mfma_tile8(&sm.HR[(rw+mm)*136], sm.W, mm, q, acc);
  __syncthreads();
  {
    const uint4* srcw = (const uint4*)(wt + WHPR_T + 128 + row*256 + part*32);
    uint4* dstw = (uint4*)&sm.W[row*136 + part*32];
#pragma unroll
    for (int j = 0; j < 4; ++j) dstw[j] = srcw[j];
  }
  __syncthreads();
  // ---- phase 2b: hp_rec += p_r @ Whpr[k>=128]; scatter agg_h ----
  mfma_tile8(&sm.PR[(rw+mm)*136], sm.W, mm, q, acc);
  {
    const int r0 = sm.recIdx[rw + q*4 + 0];
    const int r1 = sm.recIdx[rw + q*4 + 1];
    const int r2 = sm.recIdx[rw + q*4 + 2];
    const int r3 = sm.recIdx[rw + q*4 + 3];
#pragma unroll
    for (int c = 0; c < 8; ++c){
      const int col = c*16 + mm;
      const float bh = b_hpr[col];
      unsafeAtomicAdd(&aggH[(size_t)r0*DD + col], (acc[c][0] + bh) * en[c][0]);
      unsafeAtomicAdd(&aggH[(size_t)r1*DD + col], (acc[c][1] + bh) * en[c][1]);
      unsafeAtomicAdd(&aggH[(size_t)r2*DD + col], (acc[c][2] + bh) * en[c][2]);
      unsafeAtomicAdd(&aggH[(size_t)r3*DD + col], (acc[c][3] + bh) * en[c][3]);
    }
  }
  __syncthreads();
  {
    const uint4* srcw = (const uint4*)(wt + WP2_T + row*128 + part*32);
    uint4* dstw = (uint4*)&sm.W[row*136 + part*32];
#pragma unroll
    for (int j = 0; j < 4; ++j) dstw[j] = srcw[j];
  }
  __syncthreads();
  // ---- phase 3: linear_p = p_r @ Wp2; scatter agg_p ----
#pragma unroll
  for (int c = 0; c < 8; ++c) acc[c] = (f32x4){0.f,0.f,0.f,0.f};
  mfma_tile8(&sm.PR[(rw+mm)*136], sm.W, mm, q, acc);
  {
    const int r0 = sm.recIdx[rw + q*4 + 0];
    const int r1 = sm.recIdx[rw + q*4 + 1];
    const int r2 = sm.recIdx[rw + q*4 + 2];
    const int r3 = sm.recIdx[rw + q*4 + 3];
#pragma unroll
    for (int c = 0; c < 8; ++c){
      const int col = c*16 + mm;
      const float bp = b_p2[col];
      unsafeAtomicAdd(&aggP[(size_t)r0*DD + col], (acc[c][0] + bp) * en[c][0]);
      unsafeAtomicAdd(&aggP[(size_t)r1*DD + col], (acc[c][1] + bp) * en[c][1]);
      unsafeAtomicAdd(&aggP[(size_t)r2*DD + col], (acc[c][2] + bp) * en[c][2]);
      unsafeAtomicAdd(&aggP[(size_t)r3*DD + col], (acc[c][3] + bp) * en[c][3]);
    }
  }
  __syncthreads();
  if (t < 256) unsafeAtomicAdd(&gstats[t], sm.stat[t]);   // [0..127]=sum_eta [128..255]=sumsq_eta
}

// ---------------- K3: BN stats for t = hp_send + agg_h(edge-row) ----------------
struct SmemK3 {
  alignas(16) unsigned short HP[64*280];   // [hs | ps] bf16, K=256, padded stride 280
  alignas(16) unsigned short W [128*136];
  float stat[256];
};

__global__ __launch_bounds__(256, 2) void k3_hpsend(
    const int*   __restrict__ eidx,
    const unsigned short* __restrict__ hbf,
    const unsigned short* __restrict__ pbf,
    const unsigned short* __restrict__ wt,
    const float* __restrict__ aggH,
    const float* __restrict__ b_hps,
    float* __restrict__ gstats)
{
  __shared__ SmemK3 sm;
  const int t = threadIdx.x;
  const int e0 = blockIdx.x * 64;
  sm.stat[t] = 0.f;
  const int row = t >> 2, part = t & 3;
  const int er = e0 + row;
  const int snd = eidx[er];
  {
    const uint4* hs4 = (const uint4*)(hbf + (size_t)snd*DD + part*32);
    const uint4* ps4 = (const uint4*)(pbf + (size_t)snd*DD + part*32);
    uint4* dH = (uint4*)&sm.HP[row*280 + part*32];
    uint4* dP = (uint4*)&sm.HP[row*280 + 128 + part*32];
#pragma unroll
    for (int j = 0; j < 4; ++j){ dH[j] = hs4[j]; dP[j] = ps4[j]; }
  }
  {
    const int wrow = t >> 1, wpart = t & 1;
    const uint4* srcw = (const uint4*)(wt + WHPS_T + wrow*256 + wpart*64);
    uint4* dstw = (uint4*)&sm.W[wrow*136 + wpart*64];
#pragma unroll
    for (int j = 0; j < 8; ++j) dstw[j] = srcw[j];
  }
  __syncthreads();

  const int lane = t & 63, wv = t >> 6, mm = lane & 15, q = lane >> 4, rw = wv*16;
  f32x4 acc[8];
#pragma unroll
  for (int c = 0; c < 8; ++c) acc[c] = (f32x4){0.f,0.f,0.f,0.f};
  mfma_tile8(&sm.HP[(rw+mm)*280], sm.W, mm, q, acc);
  __syncthreads();
  {
    const int wrow = t >> 1, wpart = t & 1;
    const uint4* srcw = (const uint4*)(wt + WHPS_T + 128 + wrow*256 + wpart*64);
    uint4* dstw = (uint4*)&sm.W[wrow*136 + wpart*64];
#pragma unroll
    for (int j = 0; j < 8; ++j) dstw[j] = srcw[j];
  }
  __syncthreads();
  mfma_tile8(&sm.HP[(rw+mm)*280 + 128], sm.W, mm, q, acc);

#pragma unroll
  for (int c = 0; c < 8; ++c){
    const int col = c*16 + mm;
    const float bh = b_hps[col];
    float s1 = 0.f, s2 = 0.f;
#pragma unroll
    for (int g = 0; g < 4; ++g){
      const int rr = e0 + rw + q*4 + g;      // edge row, also agg index (quirk)
      float tv = acc[c][g] + bh + (rr < N_NODES ? aggH[(size_t)rr*DD + col] : 0.f);
      s1 += tv; s2 += tv*tv;
    }
    s1 += __shfl_xor(s1, 16); s1 += __shfl_xor(s1, 32);
    s2 += __shfl_xor(s2, 16); s2 += __shfl_xor(s2, 32);
    if (q == 0){
      atomicAdd(&sm.stat[col], s1);
      atomicAdd(&sm.stat[128 + col], s2);
    }
  }
  __syncthreads();
  unsafeAtomicAdd(&gstats[256 + t], sm.stat[t]);  // [256..383]=sum_t [384..511]=sumsq_t
}

// ---------------- K4: finalize BN stats ----------------
__global__ void k4_finalize(float* __restrict__ gs)
{
  const int d = threadIdx.x;  // 128
  const float invE = 1.f / (float)N_EDGES;
  float m1 = gs[d] * invE;
  float v1 = gs[128 + d] * invE - m1*m1;
  gs[512 + d] = m1; gs[640 + d] = rsqrtf(v1 + 1e-5f);
  float m2 = gs[256 + d] * invE;
  float v2 = gs[384 + d] * invE - m2*m2;
  gs[768 + d] = m2; gs[896 + d] = rsqrtf(v2 + 1e-5f);
}

// ---------------- K5: e_out = e + relu(bn(eta)) ----------------
__global__ __launch_bounds__(256) void k5_eout(
    const float* __restrict__ e, const unsigned short* __restrict__ eta,
    const float* __restrict__ gs, const float* __restrict__ gamma,
    const float* __restrict__ beta, float* __restrict__ eout)
{
  __shared__ float sg[128], sb[128], smu[128], srs[128];
  const int t = threadIdx.x;
  if (t < 128){ sg[t] = gamma[t]; sb[t] = beta[t]; }
  else { int d = t - 128; smu[d] = gs[512 + d]; srs[d] = gs[640 + d]; }
  __syncthreads();
  const size_t idx = (size_t)blockIdx.x * 256 + t;
  const int r  = (int)(idx >> 4);
  const int c0 = (int)(idx & 15) * 8;
  const float4* ein = (const float4*)(e + (size_t)r*DD + c0);
  const uint4 u = *(const uint4*)(eta + (size_t)r*DD + c0);
  float4 lo = ein[0], hi = ein[1];
  float ev[8] = {
    bf2f((unsigned short)(u.x & 0xffffu)), bf2f((unsigned short)(u.x >> 16)),
    bf2f((unsigned short)(u.y & 0xffffu)), bf2f((unsigned short)(u.y >> 16)),
    bf2f((unsigned short)(u.z & 0xffffu)), bf2f((unsigned short)(u.z >> 16)),
    bf2f((unsigned short)(u.w & 0xffffu)), bf2f((unsigned short)(u.w >> 16))};
  float ef[8] = {lo.x, lo.y, lo.z, lo.w, hi.x, hi.y, hi.z, hi.w};
  float o[8];
#pragma unroll
  for (int j = 0; j < 8; ++j){
    const int d = c0 + j;
    o[j] = ef[j] + fmaxf(0.f, sg[d]*(ev[j] - smu[d])*srs[d] + sb[d]);
  }
  float4* out = (float4*)(eout + (size_t)r*DD + c0);
  out[0] = (float4){o[0],o[1],o[2],o[3]};
  out[1] = (float4){o[4],o[5],o[6],o[7]};
}

// ---------------- K6: per-node h_out, p_out ----------------
struct SmemK6 {
  alignas(16) unsigned short HP[64*280];
  alignas(16) unsigned short W [128*136];
};

__global__ __launch_bounds__(256, 2) void k6_nodes(
    const float* __restrict__ h, const float* __restrict__ p,
    const unsigned short* __restrict__ hbf, const unsigned short* __restrict__ pbf,
    const unsigned short* __restrict__ wt,
    const float* __restrict__ aggH, const float* __restrict__ aggP,
    const int* __restrict__ lastE, const float* __restrict__ gs,
    const float* __restrict__ b_hps, const float* __restrict__ b_p1,
    const float* __restrict__ gamma, const float* __restrict__ beta,
    float* __restrict__ hout, float* __restrict__ pout)
{
  __shared__ SmemK6 sm;
  const int t = threadIdx.x;
  const int n0 = blockIdx.x * 64;
  const int row = t >> 2, part = t & 3;
  const int n = n0 + row;
  const int ncl = (n < N_NODES) ? n : (N_NODES - 1);
  {
    const uint4* hs4 = (const uint4*)(hbf + (size_t)ncl*DD + part*32);
    const uint4* ps4 = (const uint4*)(pbf + (size_t)ncl*DD + part*32);
    uint4* dH = (uint4*)&sm.HP[row*280 + part*32];
    uint4* dP = (uint4*)&sm.HP[row*280 + 128 + part*32];
#pragma unroll
    for (int j = 0; j < 4; ++j){ dH[j] = hs4[j]; dP[j] = ps4[j]; }
  }
  {
    const int wrow = t >> 1, wpart = t & 1;
    const uint4* srcw = (const uint4*)(wt + WHPS_T + wrow*256 + wpart*64);
    uint4* dstw = (uint4*)&sm.W[wrow*136 + wpart*64];
#pragma unroll
    for (int j = 0; j < 8; ++j) dstw[j] = srcw[j];
  }
  __syncthreads();

  const int lane = t & 63, wv = t >> 6, mm = lane & 15, q = lane >> 4, rw = wv*16;
  f32x4 acc_t[8], acc_q[8];
#pragma unroll
  for (int c = 0; c < 8; ++c){ acc_t[c] = (f32x4){0.f,0.f,0.f,0.f}; acc_q[c] = (f32x4){0.f,0.f,0.f,0.f}; }

  mfma_tile8(&sm.HP[(rw+mm)*280], sm.W, mm, q, acc_t);            // hs @ Whps[:128]
  __syncthreads();
  {
    const int wrow = t >> 1, wpart = t & 1;
    const uint4* srcw = (const uint4*)(wt + WHPS_T + 128 + wrow*256 + wpart*64);
    uint4* dstw = (uint4*)&sm.W[wrow*136 + wpart*64];
#pragma unroll
    for (int j = 0; j < 8; ++j) dstw[j] = srcw[j];
  }
  __syncthreads();
  mfma_tile8(&sm.HP[(rw+mm)*280 + 128], sm.W, mm, q, acc_t);      // ps @ Whps[128:]
  __syncthreads();
  {
    const int wrow = t >> 1, wpart = t & 1;
    const uint4* srcw = (const uint4*)(wt + WP1_T + wrow*128 + wpart*64);
    uint4* dstw = (uint4*)&sm.W[wrow*136 + wpart*64];
#pragma unroll
    for (int j = 0; j < 8; ++j) dstw[j] = srcw[j];
  }
  __syncthreads();
  mfma_tile8(&sm.HP[(rw+mm)*280 + 128], sm.W, mm, q, acc_q);      // ps @ Wp1

  int ie[4];
#pragma unroll
  for (int g = 0; g < 4; ++g){
    const int rr = n0 + rw + q*4 + g;
    ie[g] = (rr < N_NODES) ? lastE[rr] : -1;
  }
  const size_t POUT_SHIFT = 0;  // pout passed directly
#pragma unroll
  for (int c = 0; c < 8; ++c){
    const int col = c*16 + mm;
    const float bh = b_hps[col], bp = b_p1[col];
    const float ga = gamma[col], be = beta[col];
    const float mu = gs[768 + col], rstd = gs[896 + col];
#pragma unroll
    for (int g = 0; g < 4; ++g){
      const int nn = n0 + rw + q*4 + g;
      if (nn >= N_NODES) continue;
      const size_t off = (size_t)nn*DD + col;
      const float hn = h[off], pn = p[off];
      const int i = ie[g];
      float addh = 0.f, addp = 0.f;
      if (i >= 0){
        const float agh = (i < N_NODES) ? aggH[(size_t)i*DD + col] : 0.f;
        const float agp = (i < N_NODES) ? aggP[(size_t)i*DD + col] : 0.f;
        const float tv = acc_t[c][g] + bh + agh;
        addh = fmaxf(0.f, ga*(tv - mu)*rstd + be);
        const float qv = acc_q[c][g] + bp + agp;
        addp = tanhf(qv);
      }
      hout[off] = hn + addh;
      pout[off + POUT_SHIFT] = pn + addp;
    }
  }
}

// ---------------- launcher ----------------
extern "C" void kernel_launch(void* const* d_in, const int* in_sizes, int n_in,
                              void* d_out, int out_size, void* d_ws, size_t ws_size,
                              hipStream_t stream)
{
  const float* h     = (const float*)d_in[0];
  const float* e     = (const float*)d_in[1];
  const float* p     = (const float*)d_in[2];
  const int*   eidx  = (const int*)  d_in[3];
  const float* W_lin = (const float*)d_in[4];
  const float* b_lin = (const float*)d_in[5];
  const float* W_hps = (const float*)d_in[6];
  const float* b_hps = (const float*)d_in[7];
  const float* W_hpr = (const float*)d_in[8];
  const float* b_hpr = (const float*)d_in[9];
  const float* W_p1  = (const float*)d_in[10];
  const float* b_p1  = (const float*)d_in[11];
  const float* W_p2  = (const float*)d_in[12];
  const float* b_p2  = (const float*)d_in[13];
  const float* gamma = (const float*)d_in[14];
  const float* beta  = (const float*)d_in[15];

  char* ws = (char*)d_ws;
  unsigned short* wt    = (unsigned short*)(ws + WT_OFF);
  float*          gst   = (float*)(ws + STATS_OFF);
  int*            lastE = (int*)(ws + LAST_OFF);
  unsigned short* hbf   = (unsigned short*)(ws + HBF_OFF);
  unsigned short* pbf   = (unsigned short*)(ws + PBF_OFF);
  float*          aggH  = (float*)(ws + AGGH_OFF);
  float*          aggP  = (float*)(ws + AGGP_OFF);
  unsigned short* eta   = (unsigned short*)(ws + ETA_OFF);

  float* hout = (float*)d_out;
  float* eout = hout + (size_t)N_NODES * DD;
  float* pout = eout + (size_t)N_EDGES * DD;

  hipMemsetAsync(ws + STATS_OFF, 0, 4096, stream);
  hipMemsetAsync(ws + LAST_OFF, 0xFF, (size_t)N_NODES * 4, stream);
  hipMemsetAsync(ws + AGGH_OFF, 0, (size_t)2 * N_NODES * DD * 4, stream);  // aggH + aggP

  k0a_weights<<<448, 256, 0, stream>>>(W_lin, W_hpr, W_p2, W_hps, W_p1, wt);
  k0b_cast   <<<12500, 256, 0, stream>>>(h, p, hbf, pbf);
  k2_edge    <<<6250, 512, 0, stream>>>(e, eidx, b_lin, b_hpr, b_p2, hbf, pbf, wt,
                                        eta, aggH, aggP, lastE, gst);
  k3_hpsend  <<<12500, 256, 0, stream>>>(eidx, hbf, pbf, wt, aggH, b_hps, gst);
  k4_finalize<<<1, 128, 0, stream>>>(gst);
  k5_eout    <<<50000, 256, 0, stream>>>(e, eta, gst, gamma, beta, eout);
  k6_nodes   <<<782, 256, 0, stream>>>(h, p, hbf, pbf, wt, aggH, aggP, lastE, gst,
                                       b_hps, b_p1, gamma, beta, hout, pout);
}